// Round 4
// baseline (87.943 us; speedup 1.0000x reference)
//
#include <hip/hip_runtime.h>
#include <math.h>
#include <type_traits>

// Problem constants (reference: N=8, MA=24, DESIGN=26, RADIAL=15, SOFTENING=3, RM=5.0)
constexpr int MAC = 24;            // atoms per molecule
constexpr int DES = 26;            // sphere design points
constexpr int RAD = 15;            // radial points
constexpr int MS  = RAD * DES;     // 390 samples per atom
constexpr int MX  = MAC * MS;      // 9360 grid points per molecule
constexpr int PPG = 4;             // points per 32-lane group (4-way ILP)
constexpr int GPB = 6;             // groups per block -> 192 threads (3 waves)
constexpr int PPB = PPG * GPB;     // 24 points per block
constexpr int BPM = MX / PPB;      // 390 blocks per molecule (exact)

// compile-time loop so ds_swizzle offsets are integer-constant-expressions
template <int N, int I = 0, typename F>
__device__ __forceinline__ void static_for(F&& f) {
    if constexpr (I < N) {
        f(std::integral_constant<int, I>{});
        static_for<N, I + 1>(f);
    }
}

// broadcast lane J (within each 32-lane half) — single ds_swizzle, no addr VGPR
template <int J>
__device__ __forceinline__ float bcast32(float v) {
    return __int_as_float(__builtin_amdgcn_ds_swizzle(__float_as_int(v), (J << 5)));
}
// xor-butterfly step within 32-lane half
template <int M>
__device__ __forceinline__ float xorswz(float v) {
    return __int_as_float(__builtin_amdgcn_ds_swizzle(__float_as_int(v), (M << 10) | 0x1f));
}

// ---------------------------------------------------------------------------
// Precompute (gridded, no barriers): tables into d_ws.
//   inv_dm [nmol][24][24], conc4 [390] = {r*sx, r*sy, r*sz, sw*w},
//   cpad   [nmol][24]     = coords padded to float4
// ---------------------------------------------------------------------------
__global__ __launch_bounds__(256) void becke_pre(
    const float* __restrict__ coords, const float* __restrict__ sphere,
    const float* __restrict__ sw, int nmol,
    float* __restrict__ inv_dm, float4* __restrict__ conc4, float4* __restrict__ cpad)
{
    const int e = blockIdx.x * 256 + threadIdx.x;
    const int nidm = nmol * MAC * MAC;
    if (e < nidm) {
        int n = e / (MAC * MAC), r0 = e - n * MAC * MAC;
        int i = r0 / MAC, j = r0 - i * MAC;
        const float* cb = coords + n * MAC * 3;
        float dx = cb[i * 3 + 0] - cb[j * 3 + 0];
        float dy = cb[i * 3 + 1] - cb[j * 3 + 1];
        float dz = cb[i * 3 + 2] - cb[j * 3 + 2];
        float dd = sqrtf(dx * dx + dy * dy + dz * dz);
        inv_dm[e] = 1.0f / fmaxf(dd, 1e-12f);
        return;
    }
    const int e2 = e - nidm;
    if (e2 < MS) {
        // Gauss-Chebyshev + Becke radial quadrature, f64 (only 390 threads)
        int k = e2 / DES, d = e2 - k * DES;
        double i   = (double)k + 1.0;
        double z   = -cos(M_PI * (2.0 * i - 1.0) / (2.0 * (double)RAD));
        double omz = 1.0 - z;
        double dr  = 10.0 / (omz * omz);            // 2*RM, RM = 5.0
        double r   = 5.0 * (1.0 + z) / omz;
        double w1  = sqrt(1.0 - z * z) * dr * M_PI / (double)RAD;
        double w   = r * r * 4.0 * M_PI * w1;
        conc4[e2] = make_float4((float)(r * (double)sphere[d * 3 + 0]),
                                (float)(r * (double)sphere[d * 3 + 1]),
                                (float)(r * (double)sphere[d * 3 + 2]),
                                (float)((double)sw[d] * w));
        return;
    }
    const int e3 = e2 - MS;
    if (e3 < nmol * MAC) {
        cpad[e3] = make_float4(coords[e3 * 3 + 0], coords[e3 * 3 + 1],
                               coords[e3 * 3 + 2], 0.0f);
    }
}

// ---------------------------------------------------------------------------
// Hot kernel: 32 lanes per point-group, 4 points per group (ILP), no LDS
// arrays, no barriers. Lane i = atom row (0..23), lanes 24..31 pad.
// ---------------------------------------------------------------------------
__global__ __launch_bounds__(192) void becke_main(
    const float4* __restrict__ cpad,    // [nmol*24]
    const float*  __restrict__ inv_dm,  // [nmol*24*24]
    const float4* __restrict__ conc4,   // [390]
    float* __restrict__ og,             // [nmol, MX, 3]
    float* __restrict__ odv,            // [nmol, MX, 24, 3]
    float* __restrict__ ow)             // [nmol, MX]
{
    const int tid = threadIdx.x;
    const int l   = tid & 31;
    const int b   = blockIdx.x;
    const int n   = b / BPM;
    const int bm  = b - n * BPM;
    const int s0  = bm * PPB + (tid >> 5) * PPG;   // first point of this group
    const bool act = (l < MAC);
    const int  i   = act ? l : (MAC - 1);

    int ap[PPG], tp[PPG];
    #pragma unroll
    for (int p = 0; p < PPG; ++p) {
        int sp = s0 + p;
        ap[p] = sp / MS;
        tp[p] = sp - ap[p] * MS;
    }

    const float4 ci = cpad[n * MAC + i];

    float gx[PPG], gy[PPG], gz[PPG], wt[PPG];
    #pragma unroll
    for (int p = 0; p < PPG; ++p) {
        float4 cc = conc4[tp[p]];
        float4 ca = cpad[n * MAC + ap[p]];
        gx[p] = ca.x + cc.x;
        gy[p] = ca.y + cc.y;
        gz[p] = ca.z + cc.z;
        wt[p] = cc.w;
    }

    const size_t sgb = (size_t)n * MX + s0;

    float rx[PPG];
    #pragma unroll
    for (int p = 0; p < PPG; ++p) {
        float dx = gx[p] - ci.x;
        float dy = gy[p] - ci.y;
        float dz = gz[p] - ci.z;
        if (act) {
            float* dvp = odv + ((sgb + p) * MAC + i) * 3;
            dvp[0] = dx; dvp[1] = dy; dvp[2] = dz;
        }
        rx[p] = sqrtf(dx * dx + dy * dy + dz * dz);
    }

    // lane's inv_dm row: 6 x dwordx4
    float inv[MAC];
    {
        const float* irow = inv_dm + (n * MAC + i) * MAC;
        #pragma unroll
        for (int q = 0; q < MAC / 4; ++q) {
            float4 v = *reinterpret_cast<const float4*>(irow + q * 4);
            inv[q * 4 + 0] = v.x; inv[q * 4 + 1] = v.y;
            inv[q * 4 + 2] = v.z; inv[q * 4 + 3] = v.w;
        }
    }

    // Becke row products (diagonal included: s(0)=0.5 exactly, undone by *2)
    float prod[PPG] = {1.0f, 1.0f, 1.0f, 1.0f};
    static_for<MAC>([&](auto jc) {
        constexpr int j = jc.value;
        const float aj = inv[j];
        #pragma unroll
        for (int p = 0; p < PPG; ++p) {
            float rj = bcast32<j>(rx[p]);
            float mu = (rx[p] - rj) * aj;
            mu *= fmaf(mu * mu, -0.5f, 1.5f);   // softening pass 1
            mu *= fmaf(mu * mu, -0.5f, 1.5f);   // softening pass 2
            prod[p] *= fmaf(mu, -0.5f, 0.5f);   // s = 0.5*(1-mu)
        }
    });

    #pragma unroll
    for (int p = 0; p < PPG; ++p) {
        float cell = act ? (prod[p] + prod[p]) : 0.0f;
        float sum = cell;
        sum += xorswz<1>(sum);
        sum += xorswz<2>(sum);
        sum += xorswz<4>(sum);
        sum += xorswz<8>(sum);
        sum += xorswz<16>(sum);
        if (l == ap[p])   // lane a holds cell_a; 2% threshold -> rcp is fine
            ow[sgb + p] = cell * __builtin_amdgcn_rcpf(sum) * wt[p];
    }

    if (l >= MAC && l < MAC + PPG) {   // pad lanes 24..27 store grid points
        int p = l - MAC;
        float* gp = og + (sgb + p) * 3;
        gp[0] = gx[p]; gp[1] = gy[p]; gp[2] = gz[p];
    }
}

extern "C" void kernel_launch(void* const* d_in, const int* in_sizes, int n_in,
                              void* d_out, int out_size, void* d_ws, size_t ws_size,
                              hipStream_t stream) {
    // inputs: [0]=labels (unused), [1]=coords f32 [N,24,3],
    //         [2]=sphere f32 [26,3], [3]=sphere_weights f32 [26]
    const float* coords = (const float*)d_in[1];
    const float* sphere = (const float*)d_in[2];
    const float* sw     = (const float*)d_in[3];

    const int nmol = in_sizes[1] / (MAC * 3);   // 8

    float*  ws     = (float*)d_ws;
    float*  inv_dm = ws;                                        // nmol*576 floats
    float4* conc4  = (float4*)(inv_dm + (size_t)nmol * MAC * MAC); // 390 float4 (16B-aligned)
    float4* cpad   = conc4 + MS;                                // nmol*24 float4

    float* o     = (float*)d_out;
    float* ogrid = o;                                        // [N, MX, 3]
    float* odv   = ogrid + (size_t)nmol * MX * 3;            // [N, MX, 24, 3]
    float* owt   = odv + (size_t)nmol * MX * MAC * 3;        // [N, MX]

    const int pre_elems  = nmol * MAC * MAC + MS + nmol * MAC;
    const int pre_blocks = (pre_elems + 255) / 256;
    becke_pre<<<dim3(pre_blocks), dim3(256), 0, stream>>>(
        coords, sphere, sw, nmol, inv_dm, conc4, cpad);

    becke_main<<<dim3(nmol * BPM), dim3(192), 0, stream>>>(
        cpad, inv_dm, conc4, ogrid, odv, owt);
}